// Round 1
// baseline (962.500 us; speedup 1.0000x reference)
//
#include <hip/hip_runtime.h>

// FiniteDifferenceGradient: periodic central difference on (4,256,256,256) f32.
// out[b][c][x][y][z], c in {gx, gy, gz}, spacing = 1 -> grad = (v[+1]-v[-1])*0.5
//
// Layout constants (power-of-two shifts):
//   z stride 1, y stride 256 (<<8), x stride 65536 (<<16), b stride 1<<24.
// One thread per float4 along z (z4 in [0,64)).

__global__ __launch_bounds__(256) void fdgrad_kernel(
    const float* __restrict__ vin, float* __restrict__ vout) {
    const unsigned tid = blockIdx.x * 256u + threadIdx.x;

    const unsigned z4 = tid & 63u;          // float4 index along z
    const unsigned y  = (tid >> 6) & 255u;
    const unsigned x  = (tid >> 14) & 255u;
    const unsigned b  = tid >> 22;

    const float4* __restrict__ vin4 = reinterpret_cast<const float4*>(vin);
    float4* __restrict__ vout4      = reinterpret_cast<float4*>(vout);

    const unsigned xp = (x == 255u) ? 0u : x + 1u;
    const unsigned xm = (x == 0u) ? 255u : x - 1u;
    const unsigned yp = (y == 255u) ? 0u : y + 1u;
    const unsigned ym = (y == 0u) ? 255u : y - 1u;

    // float4-granular indices: (b<<22) + (x<<14) + (y<<6) + z4
    const unsigned base_b = b << 22;
    const unsigned idx_c  = base_b + (x << 14) + (y << 6) + z4;
    const unsigned idx_xp = base_b + (xp << 14) + (y << 6) + z4;
    const unsigned idx_xm = base_b + (xm << 14) + (y << 6) + z4;
    const unsigned idx_yp = base_b + (x << 14) + (yp << 6) + z4;
    const unsigned idx_ym = base_b + (x << 14) + (ym << 6) + z4;

    const float4 c  = vin4[idx_c];
    const float4 vxp = vin4[idx_xp];
    const float4 vxm = vin4[idx_xm];
    const float4 vyp = vin4[idx_yp];
    const float4 vym = vin4[idx_ym];

    // z halo (scalar, with periodic wrap within the row)
    const unsigned z0 = z4 << 2;
    const unsigned row = (b << 24) + (x << 16) + (y << 8);
    const float zm = vin[row + ((z4 == 0u) ? 255u : z0 - 1u)];
    const float zp = vin[row + ((z4 == 63u) ? 0u : z0 + 4u)];

    float4 gx, gy, gz;
    gx.x = (vxp.x - vxm.x) * 0.5f;
    gx.y = (vxp.y - vxm.y) * 0.5f;
    gx.z = (vxp.z - vxm.z) * 0.5f;
    gx.w = (vxp.w - vxm.w) * 0.5f;

    gy.x = (vyp.x - vym.x) * 0.5f;
    gy.y = (vyp.y - vym.y) * 0.5f;
    gy.z = (vyp.z - vym.z) * 0.5f;
    gy.w = (vyp.w - vym.w) * 0.5f;

    gz.x = (c.y - zm) * 0.5f;
    gz.y = (c.z - c.x) * 0.5f;
    gz.z = (c.w - c.y) * 0.5f;
    gz.w = (zp - c.z) * 0.5f;

    // out float4 index: ((b*3+c)<<22) + (x<<14) + (y<<6) + z4
    const unsigned spatial = (x << 14) + (y << 6) + z4;
    vout4[((b * 3u + 0u) << 22) + spatial] = gx;
    vout4[((b * 3u + 1u) << 22) + spatial] = gy;
    vout4[((b * 3u + 2u) << 22) + spatial] = gz;
}

extern "C" void kernel_launch(void* const* d_in, const int* in_sizes, int n_in,
                              void* d_out, int out_size, void* d_ws, size_t ws_size,
                              hipStream_t stream) {
    const float* vin = (const float*)d_in[0];
    float* vout = (float*)d_out;
    // total float4 threads: 4*256*256*64 = 16,777,216 -> 65536 blocks of 256
    fdgrad_kernel<<<65536, 256, 0, stream>>>(vin, vout);
}